// Round 6
// baseline (552.185 us; speedup 1.0000x reference)
//
#include <hip/hip_runtime.h>
#include <hip/hip_bf16.h>

// RNNCell scan: T=512, B=16384, H=32.
// 8 batches per wave -> 2048 waves = 2 waves/SIMD (TLP to hide the serial
// dependency chain). Nonlinear work in compact layout (batch=lane&7,
// h = 4*(lane>>3)+i : 4 values/lane, half of R5). MFMA B-fragments rebuilt
// via 8 ds_bpermute (src = lane&55 / +8); columns 8-15 duplicate batches
// 0-7 bit-identically. Compact layout == tile-select((lane>>3)&1) of the
// MFMA D layout, so post-GEMM select is 4 cndmask and the epilogue needs no
// redistribution. bf16 hi/lo trunc split, 3 MFMAs/tile, select-free trans.

#define T_STEPS 512
#define B_TOT   16384

typedef __attribute__((ext_vector_type(8))) short short8;
typedef __attribute__((ext_vector_type(4))) float f32x4;
typedef __attribute__((ext_vector_type(4))) int   i32x4;

__device__ __forceinline__ short8 as_s8(i32x4 v) {
    union { i32x4 i; short8 s; } u; u.i = v; return u.s;
}

#define NLOG2E -1.44269504088896340736f
#define LN2     0.69314718055994530942f

// sigma(z) = 1/(1+e^-z), select-free, overflow-safe
__device__ __forceinline__ float sigm(float z) {
    const float t = __builtin_amdgcn_exp2f(z * NLOG2E);
    return __builtin_amdgcn_rcpf(1.0f + t);
}

// softplus + sigmoid sharing one exp: sp(z) = z - ln(sigma(z))
__device__ __forceinline__ void sp_sig(float z, float& sp, float& sg) {
    const float t = __builtin_amdgcn_exp2f(z * NLOG2E);
    const float r = __builtin_amdgcn_rcpf(1.0f + t);
    sg = r;
    sp = fmaf(-LN2, __builtin_amdgcn_logf(r), z);
}

// exact trunc split: hi = trunc-bf16 pair, lo = exact residual (trunc-packed)
__device__ __forceinline__ void sp2t(float x0, float x1, int& hi, int& lo) {
    const unsigned h0 = __float_as_uint(x0) & 0xffff0000u;
    const unsigned h1 = __float_as_uint(x1) & 0xffff0000u;
    hi = (int)(h1 | (h0 >> 16));
    const float l0 = x0 - __uint_as_float(h0);
    const float l1 = x1 - __uint_as_float(h1);
    lo = (int)((__float_as_uint(l1) & 0xffff0000u) | (__float_as_uint(l0) >> 16));
}

__device__ __forceinline__ int bperm(int idx, int v) {
    return __builtin_amdgcn_ds_bpermute(idx, v);
}

// DPP row_ror:8 add-source (xor8 within a row of 16)
__device__ __forceinline__ float dpp_ror8(float x) {
    return __int_as_float(
        __builtin_amdgcn_update_dpp(0, __float_as_int(x), 0x128, 0xF, 0xF, 1));
}

#define MFMA(A, B, C) __builtin_amdgcn_mfma_f32_16x16x32_bf16((A), (B), (C), 0, 0, 0)

__global__ __launch_bounds__(256, 2) void rnn_scan(
    const float* __restrict__ eps, const float* __restrict__ hs,
    const float* __restrict__ W1,  const float* __restrict__ b1,
    const float* __restrict__ W2,  const float* __restrict__ b2,
    const float* __restrict__ W3,  float* __restrict__ out)
{
    const int lane = threadIdx.x & 63;
    const int wv   = threadIdx.x >> 6;
    const int bat  = lane & 7;           // batch within wave
    const int hg   = lane >> 3;          // compact h-group: h = 4*hg + i
    const int c    = lane & 15;          // MFMA column
    const int q    = lane >> 4;          // MFMA quad
    const int bidx = blockIdx.x * 32 + wv * 8 + bat;

    // compact-layout per-lane weights (h = 4*hg + i)
    float W1e[4], W1g[4], b1P[4], W3P[4];
#pragma unroll
    for (int i = 0; i < 4; ++i) {
        const int h = 4 * hg + i;
        W1e[i] = W1[h];
        W1g[i] = W1[32 + h];
        b1P[i] = b1[h];
        W3P[i] = W3[h];
    }
    // D-layout b2 for acc init (h = 8q + i)
    float b2D[8];
#pragma unroll
    for (int i = 0; i < 8; ++i) b2D[i] = b2[8 * q + i];

    // A fragments (hi/lo trunc split), row-permuted h(m,t)=8*(m>>2)+4t+(m&3)
    i32x4 A1h[2], A1l[2], A2h[2], A2l[2];
#pragma unroll
    for (int t = 0; t < 2; ++t) {
        const int hc = 8 * (c >> 2) + 4 * t + (c & 3);
#pragma unroll
        for (int p = 0; p < 4; ++p) {
            int th, tl;
            const float x0 = W2[(8 * q + 2 * p) * 32 + hc];
            const float x1 = W2[(8 * q + 2 * p + 1) * 32 + hc];
            sp2t(x0, x1, th, tl);
            A1h[t][p] = th; A1l[t][p] = tl;
            const float y0 = W2[hc * 32 + 8 * q + 2 * p];
            const float y1 = W2[hc * 32 + 8 * q + 2 * p + 1];
            sp2t(y0, y1, th, tl);
            A2h[t][p] = th; A2l[t][p] = tl;
        }
    }

    // bpermute byte-indices: compact source lanes for this B-fragment lane
    const int i0   = (lane & 55) << 2;   // (lane&7) + 16*(lane>>4)
    const int i1   = i0 + 32;            // +8 lanes
    const int ix16 = (lane ^ 16) << 2;
    const int ix32 = (lane ^ 32) << 2;
    const bool tsel = (lane >> 3) & 1;   // which D-tile this lane owns

    const float* pe = eps + bidx + B_TOT;   // prefetch cursor (t+1)
    const float* ph = hs  + bidx + B_TOT;
    float*       po = out + bidx;

    float gamma = 0.0f;
    float e_cur = eps[bidx];
    float h_cur = hs[bidx];

#define STEP_BODY(PF)                                                          \
    {                                                                          \
        float e_nxt = 0.f, h_nxt = 0.f;                                        \
        if (PF) { e_nxt = pe[0]; h_nxt = ph[0]; pe += B_TOT; ph += B_TOT; }    \
        /* phase 1: z1 -> a1 (softplus), g1 (sigmoid); 4 values/lane */        \
        float a1[4], g1[4];                                                    \
        _Pragma("unroll")                                                      \
        for (int i = 0; i < 4; ++i) {                                          \
            const float z = fmaf(e_cur, W1e[i], fmaf(gamma, W1g[i], b1P[i]));  \
            sp_sig(z, a1[i], g1[i]);                                           \
        }                                                                      \
        int H0, L0, H1, L1;                                                    \
        sp2t(a1[0], a1[1], H0, L0);                                            \
        sp2t(a1[2], a1[3], H1, L1);                                            \
        /* rebuild B fragment from compact layout */                           \
        i32x4 bh, bl;                                                          \
        bh[0] = bperm(i0, H0); bh[1] = bperm(i0, H1);                          \
        bh[2] = bperm(i1, H0); bh[3] = bperm(i1, H1);                          \
        bl[0] = bperm(i0, L0); bl[1] = bperm(i0, L1);                          \
        bl[2] = bperm(i1, L0); bl[3] = bperm(i1, L1);                          \
        /* GEMM1: z2 = (Ah+Al)Bh + Ah*Bl (+b2) */                              \
        const short8 Bh = as_s8(bh), Bl = as_s8(bl);                           \
        f32x4 zA0 = {b2D[0], b2D[1], b2D[2], b2D[3]};                          \
        f32x4 zA1 = {b2D[4], b2D[5], b2D[6], b2D[7]};                          \
        f32x4 zB0 = {0.f, 0.f, 0.f, 0.f};                                      \
        f32x4 zB1 = {0.f, 0.f, 0.f, 0.f};                                      \
        zA0 = MFMA(as_s8(A1h[0]), Bh, zA0);                                    \
        zA1 = MFMA(as_s8(A1h[1]), Bh, zA1);                                    \
        zB0 = MFMA(as_s8(A1h[0]), Bl, zB0);                                    \
        zB1 = MFMA(as_s8(A1h[1]), Bl, zB1);                                    \
        zA0 = MFMA(as_s8(A1l[0]), Bh, zA0);                                    \
        zA1 = MFMA(as_s8(A1l[1]), Bh, zA1);                                    \
        /* tile-select to compact layout; v2 = sigm(z2)*W3 (4/lane) */         \
        float v2[4];                                                           \
        _Pragma("unroll")                                                      \
        for (int i = 0; i < 4; ++i) {                                          \
            const float zlo = zA0[i] + zB0[i];                                 \
            const float zhi = zA1[i] + zB1[i];                                 \
            v2[i] = sigm(tsel ? zhi : zlo) * W3P[i];                           \
        }                                                                      \
        sp2t(v2[0], v2[1], H0, L0);                                            \
        sp2t(v2[2], v2[3], H1, L1);                                            \
        i32x4 vh, vl;                                                          \
        vh[0] = bperm(i0, H0); vh[1] = bperm(i0, H1);                          \
        vh[2] = bperm(i1, H0); vh[3] = bperm(i1, H1);                          \
        vl[0] = bperm(i0, L0); vl[1] = bperm(i0, L1);                          \
        vl[2] = bperm(i1, L0); vl[3] = bperm(i1, L1);                          \
        /* GEMM2: s1 = (Ah+Al)Vh + Ah*Vl */                                    \
        const short8 Vh = as_s8(vh), Vl = as_s8(vl);                           \
        f32x4 sA0 = {0.f, 0.f, 0.f, 0.f};                                      \
        f32x4 sA1 = {0.f, 0.f, 0.f, 0.f};                                      \
        f32x4 sB0 = {0.f, 0.f, 0.f, 0.f};                                      \
        f32x4 sB1 = {0.f, 0.f, 0.f, 0.f};                                      \
        sA0 = MFMA(as_s8(A2h[0]), Vh, sA0);                                    \
        sA1 = MFMA(as_s8(A2h[1]), Vh, sA1);                                    \
        sB0 = MFMA(as_s8(A2h[0]), Vl, sB0);                                    \
        sB1 = MFMA(as_s8(A2h[1]), Vl, sB1);                                    \
        sA0 = MFMA(as_s8(A2l[0]), Vh, sA0);                                    \
        sA1 = MFMA(as_s8(A2l[1]), Vh, sA1);                                    \
        /* epilogue in compact layout: v1 = g1.*s1, partial g = v1@W1^T */     \
        float p0 = 0.f, p1 = 0.f;                                              \
        _Pragma("unroll")                                                      \
        for (int i = 0; i < 4; ++i) {                                          \
            const float slo = sA0[i] + sB0[i];                                 \
            const float shi = sA1[i] + sB1[i];                                 \
            const float v = g1[i] * (tsel ? shi : slo);                        \
            p0 = fmaf(v, W1e[i], p0);                                          \
            p1 = fmaf(v, W1g[i], p1);                                          \
        }                                                                      \
        /* reduce over the batch's 8 lanes: xor8 (DPP) + xor16 + xor32 */      \
        p0 += dpp_ror8(p0);  p1 += dpp_ror8(p1);                               \
        p0 += __int_as_float(bperm(ix16, __float_as_int(p0)));                 \
        p1 += __int_as_float(bperm(ix16, __float_as_int(p1)));                 \
        p0 += __int_as_float(bperm(ix32, __float_as_int(p0)));                 \
        p1 += __int_as_float(bperm(ix32, __float_as_int(p1)));                 \
        po[0] = p0;  po += B_TOT;                                              \
        gamma = fmaf(h_cur, -p1, gamma);                                       \
        e_cur = e_nxt;                                                         \
        h_cur = h_nxt;                                                         \
    }

    for (int t = 0; t < T_STEPS - 1; ++t) STEP_BODY(1)
    STEP_BODY(0)
#undef STEP_BODY
}

extern "C" void kernel_launch(void* const* d_in, const int* in_sizes, int n_in,
                              void* d_out, int out_size, void* d_ws, size_t ws_size,
                              hipStream_t stream) {
    const float* eps = (const float*)d_in[0];
    const float* hs  = (const float*)d_in[1];
    const float* W1  = (const float*)d_in[2];
    const float* b1  = (const float*)d_in[3];
    const float* W2  = (const float*)d_in[4];
    const float* b2  = (const float*)d_in[5];
    const float* W3  = (const float*)d_in[6];
    float* out = (float*)d_out;

    // 32 batches per 256-thread block (4 waves x 8) -> 512 blocks,
    // 2048 waves = 2 waves/SIMD
    dim3 grid(B_TOT / 32), block(256);
    hipLaunchKernelGGL(rnn_scan, grid, block, 0, stream,
                       eps, hs, W1, b1, W2, b2, W3, out);
}

// Round 7
// 443.565 us; speedup vs baseline: 1.2449x; 1.2449x over previous
//
#include <hip/hip_runtime.h>

// RNNCell scan: T=512, B=16384, H=32.
// 8 batches/wave -> 2048 waves = 2 waves/SIMD (TLP hides the serial chain).
// Nonlinear work in compact layout (batch = lane&7, h = 4*(lane>>3)+i).
// MFMA B-fragments rebuilt from the compact layout with row_ror:8 DPP +
// cndmask on the VALU pipe (row-local fan-in; no ds_bpermute -> no DS
// contention). Compact layout == tile-select((lane>>3)&1) of the MFMA D
// layout, so post-GEMM select is 4 cndmask and the epilogue needs no
// redistribution. bf16 hi/lo trunc split (v_perm packing), 3 MFMAs/tile.
// -log2e folded into GEMM1's A/bias so v2-sigmoid needs no scaling mul.
// p0 store deferred one iteration to hide the bperm wait.

#define T_STEPS 512
#define B_TOT   16384
#define STRIDE_B 65536            // B_TOT * sizeof(float)

typedef __attribute__((ext_vector_type(8))) short short8;
typedef __attribute__((ext_vector_type(4))) float f32x4;
typedef __attribute__((ext_vector_type(4))) int   i32x4;

__device__ __forceinline__ short8 as_s8(i32x4 v) {
    union { i32x4 i; short8 s; } u; u.i = v; return u.s;
}

#define NLOG2E -1.44269504088896340736f
#define LN2     0.69314718055994530942f

// softplus + sigmoid sharing one exp: sp(z) = z - ln(sigma(z))
__device__ __forceinline__ void sp_sig(float z, float& sp, float& sg) {
    const float t = __builtin_amdgcn_exp2f(z * NLOG2E);
    const float r = __builtin_amdgcn_rcpf(1.0f + t);
    sg = r;
    sp = fmaf(-LN2, __builtin_amdgcn_logf(r), z);
}

// sigmoid from pre-scaled zs = -log2e * z
__device__ __forceinline__ float sigm2(float zs) {
    const float t = __builtin_amdgcn_exp2f(zs);
    return __builtin_amdgcn_rcpf(1.0f + t);
}

// exact trunc split, v_perm packing: hi/lo bf16 pairs, lo = exact residual
__device__ __forceinline__ void sp2t(float x0, float x1, int& hi, int& lo) {
    const unsigned h0 = __float_as_uint(x0) & 0xffff0000u;
    const unsigned h1 = __float_as_uint(x1) & 0xffff0000u;
    hi = (int)__builtin_amdgcn_perm(__float_as_uint(x1), __float_as_uint(x0),
                                    0x07060302u);
    const float l0 = x0 - __uint_as_float(h0);
    const float l1 = x1 - __uint_as_float(h1);
    lo = (int)__builtin_amdgcn_perm(__float_as_uint(l1), __float_as_uint(l0),
                                    0x07060302u);
}

// row_ror:8 — swap the two 8-lane halves of each 16-lane row (VALU pipe)
__device__ __forceinline__ int ror8(int x) {
    return __builtin_amdgcn_update_dpp(0, x, 0x128, 0xF, 0xF, 1);
}
__device__ __forceinline__ float ror8f(float x) {
    return __int_as_float(ror8(__float_as_int(x)));
}
__device__ __forceinline__ float bpermf(int idx, float v) {
    return __int_as_float(__builtin_amdgcn_ds_bpermute(idx, __float_as_int(v)));
}

#define MFMA(A, B, C) __builtin_amdgcn_mfma_f32_16x16x32_bf16((A), (B), (C), 0, 0, 0)

__global__ __launch_bounds__(256, 2) void rnn_scan(
    const float* __restrict__ eps, const float* __restrict__ hs,
    const float* __restrict__ W1,  const float* __restrict__ b1,
    const float* __restrict__ W2,  const float* __restrict__ b2,
    const float* __restrict__ W3,  float* __restrict__ out)
{
    const int lane = threadIdx.x & 63;
    const int wv   = threadIdx.x >> 6;
    const int bat  = lane & 7;           // batch within wave
    const int hg   = lane >> 3;          // compact h-group: h = 4*hg + i
    const int c    = lane & 15;          // MFMA column
    const int q    = lane >> 4;          // MFMA quad
    const int bidx = blockIdx.x * 32 + wv * 8 + bat;

    // compact-layout per-lane weights (h = 4*hg + i)
    float W1e[4], W1g[4], b1P[4], W3P[4];
#pragma unroll
    for (int i = 0; i < 4; ++i) {
        const int h = 4 * hg + i;
        W1e[i] = W1[h];
        W1g[i] = W1[32 + h];
        b1P[i] = b1[h];
        W3P[i] = W3[h];
    }
    // D-layout b2 (h = 8q + i), pre-scaled by -log2e (GEMM1 outputs zs2)
    float b2s[8];
#pragma unroll
    for (int i = 0; i < 8; ++i) b2s[i] = b2[8 * q + i] * NLOG2E;

    // A fragments (hi/lo trunc split), row-permuted h(m,t)=8*(m>>2)+4t+(m&3).
    // A1 (GEMM1, z2^T = W2^T@a1^T) is pre-scaled by -log2e; A2 natural.
    i32x4 A1h[2], A1l[2], A2h[2], A2l[2];
#pragma unroll
    for (int t = 0; t < 2; ++t) {
        const int hc = 8 * (c >> 2) + 4 * t + (c & 3);
#pragma unroll
        for (int p = 0; p < 4; ++p) {
            int th, tl;
            const float x0 = W2[(8 * q + 2 * p) * 32 + hc] * NLOG2E;
            const float x1 = W2[(8 * q + 2 * p + 1) * 32 + hc] * NLOG2E;
            sp2t(x0, x1, th, tl);
            A1h[t][p] = th; A1l[t][p] = tl;
            const float y0 = W2[hc * 32 + 8 * q + 2 * p];
            const float y1 = W2[hc * 32 + 8 * q + 2 * p + 1];
            sp2t(y0, y1, th, tl);
            A2h[t][p] = th; A2l[t][p] = tl;
        }
    }

    const bool hiHalf = (c & 8) != 0;    // this lane sits in row-half 8..15
    const bool tsel   = (hg & 1) != 0;   // which D-tile this lane owns
    const int  ix16   = (lane ^ 16) << 2;
    const int  ix32   = (lane ^ 32) << 2;

    float gamma = 0.0f;
    float h_cur = hs[bidx];
    float pre[4];
    {
        const float e0 = eps[bidx];
#pragma unroll
        for (int i = 0; i < 4; ++i) pre[i] = fmaf(e0, W1e[i], b1P[i]);
    }
    int voff_ld = bidx * 4 + STRIDE_B;   // loads for step t+1
    int voff_st = bidx * 4;              // store for step t-1
    float p0_pend = 0.0f;

#define STEP_BODY(PF, ST)                                                      \
    {                                                                          \
        if (ST) {                                                              \
            *(float*)((char*)out + voff_st) = p0_pend;                         \
            voff_st += STRIDE_B;                                               \
        }                                                                      \
        float e_nxt = 0.f, h_nxt = 0.f;                                        \
        if (PF) {                                                              \
            e_nxt = *(const float*)((const char*)eps + voff_ld);               \
            h_nxt = *(const float*)((const char*)hs + voff_ld);                \
            voff_ld += STRIDE_B;                                               \
        }                                                                      \
        /* z1 = pre + gamma*W1g; a1 = softplus, g1 = sigmoid (4/lane) */       \
        float a1[4], g1[4];                                                    \
        _Pragma("unroll")                                                      \
        for (int i = 0; i < 4; ++i) {                                          \
            const float z = fmaf(gamma, W1g[i], pre[i]);                       \
            sp_sig(z, a1[i], g1[i]);                                           \
        }                                                                      \
        int H0, L0, H1, L1;                                                    \
        sp2t(a1[0], a1[1], H0, L0);                                            \
        sp2t(a1[2], a1[3], H1, L1);                                            \
        /* B fragment from compact layout: row-half swap via DPP + select */   \
        i32x4 bh, bl;                                                          \
        {                                                                      \
            const int rH0 = ror8(H0), rH1 = ror8(H1);                          \
            const int rL0 = ror8(L0), rL1 = ror8(L1);                          \
            bh[0] = hiHalf ? rH0 : H0;  bh[1] = hiHalf ? rH1 : H1;             \
            bh[2] = hiHalf ? H0 : rH0;  bh[3] = hiHalf ? H1 : rH1;             \
            bl[0] = hiHalf ? rL0 : L0;  bl[1] = hiHalf ? rL1 : L1;             \
            bl[2] = hiHalf ? L0 : rL0;  bl[3] = hiHalf ? L1 : rL1;             \
        }                                                                      \
        /* GEMM1 (pre-scaled): zs2 = -log2e*(W2^T a1 + b2); 3-deep chains */   \
        const short8 Bh = as_s8(bh), Bl = as_s8(bl);                           \
        f32x4 z0 = {b2s[0], b2s[1], b2s[2], b2s[3]};                           \
        f32x4 z1 = {b2s[4], b2s[5], b2s[6], b2s[7]};                           \
        z0 = MFMA(as_s8(A1h[0]), Bh, z0);                                      \
        z1 = MFMA(as_s8(A1h[1]), Bh, z1);                                      \
        z0 = MFMA(as_s8(A1h[0]), Bl, z0);                                      \
        z1 = MFMA(as_s8(A1h[1]), Bl, z1);                                      \
        z0 = MFMA(as_s8(A1l[0]), Bh, z0);                                      \
        z1 = MFMA(as_s8(A1l[1]), Bh, z1);                                      \
        /* tile-select to compact; v2 = sigm(z2)*W3 */                         \
        float v2[4];                                                           \
        _Pragma("unroll")                                                      \
        for (int i = 0; i < 4; ++i)                                            \
            v2[i] = sigm2(tsel ? z1[i] : z0[i]) * W3P[i];                      \
        sp2t(v2[0], v2[1], H0, L0);                                            \
        sp2t(v2[2], v2[3], H1, L1);                                            \
        i32x4 vh, vl;                                                          \
        {                                                                      \
            const int rH0 = ror8(H0), rH1 = ror8(H1);                          \
            const int rL0 = ror8(L0), rL1 = ror8(L1);                          \
            vh[0] = hiHalf ? rH0 : H0;  vh[1] = hiHalf ? rH1 : H1;             \
            vh[2] = hiHalf ? H0 : rH0;  vh[3] = hiHalf ? H1 : rH1;             \
            vl[0] = hiHalf ? rL0 : L0;  vl[1] = hiHalf ? rL1 : L1;             \
            vl[2] = hiHalf ? L0 : rL0;  vl[3] = hiHalf ? L1 : rL1;             \
        }                                                                      \
        /* GEMM2 (natural): s1 = W2 v2; 3-deep chains */                       \
        const short8 Vh = as_s8(vh), Vl = as_s8(vl);                           \
        f32x4 s0 = {0.f, 0.f, 0.f, 0.f};                                       \
        f32x4 s1 = {0.f, 0.f, 0.f, 0.f};                                       \
        s0 = MFMA(as_s8(A2h[0]), Vh, s0);                                      \
        s1 = MFMA(as_s8(A2h[1]), Vh, s1);                                      \
        s0 = MFMA(as_s8(A2h[0]), Vl, s0);                                      \
        s1 = MFMA(as_s8(A2h[1]), Vl, s1);                                      \
        s0 = MFMA(as_s8(A2l[0]), Vh, s0);                                      \
        s1 = MFMA(as_s8(A2l[1]), Vh, s1);                                      \
        /* epilogue: v1 = g1.*s1; partial g = v1@W1^T */                       \
        float p0 = 0.f, p1 = 0.f;                                              \
        _Pragma("unroll")                                                      \
        for (int i = 0; i < 4; ++i) {                                          \
            const float v = g1[i] * (tsel ? s1[i] : s0[i]);                    \
            p0 = fmaf(v, W1e[i], p0);                                          \
            p1 = fmaf(v, W1g[i], p1);                                          \
        }                                                                      \
        /* reduce over the batch's 8 lanes: xor8 (DPP) + xor16/xor32 (DS) */   \
        p0 += ror8f(p0);  p1 += ror8f(p1);                                     \
        p1 += bpermf(ix16, p1);  p0 += bpermf(ix16, p0);                       \
        p1 += bpermf(ix32, p1);  p0 += bpermf(ix32, p0);                       \
        p0_pend = p0;                    /* store deferred to next iter */     \
        gamma = fmaf(h_cur, -p1, gamma);                                       \
        h_cur = h_nxt;                                                         \
        if (PF) {                                                              \
            _Pragma("unroll")                                                  \
            for (int i = 0; i < 4; ++i) pre[i] = fmaf(e_nxt, W1e[i], b1P[i]);  \
        }                                                                      \
    }

    STEP_BODY(1, 0)                                      // t = 0
    for (int t = 1; t < T_STEPS - 1; ++t) STEP_BODY(1, 1)
    STEP_BODY(0, 1)                                      // t = 511
    *(float*)((char*)out + voff_st) = p0_pend;           // flush t = 511
#undef STEP_BODY
}

extern "C" void kernel_launch(void* const* d_in, const int* in_sizes, int n_in,
                              void* d_out, int out_size, void* d_ws, size_t ws_size,
                              hipStream_t stream) {
    const float* eps = (const float*)d_in[0];
    const float* hs  = (const float*)d_in[1];
    const float* W1  = (const float*)d_in[2];
    const float* b1  = (const float*)d_in[3];
    const float* W2  = (const float*)d_in[4];
    const float* b2  = (const float*)d_in[5];
    const float* W3  = (const float*)d_in[6];
    float* out = (float*)d_out;

    // 32 batches per 256-thread block (4 waves x 8) -> 512 blocks,
    // 2048 waves = 2 waves/SIMD
    dim3 grid(B_TOT / 32), block(256);
    hipLaunchKernelGGL(rnn_scan, grid, block, 0, stream,
                       eps, hs, W1, b1, W2, b2, W3, out);
}